// Round 4
// baseline (182.248 us; speedup 1.0000x reference)
//
#include <hip/hip_runtime.h>
#include <math.h>

typedef _Float16 half_t;
typedef _Float16 h2 __attribute__((ext_vector_type(2)));
typedef unsigned int uint;
typedef unsigned long long u64;

#define TPB 256

// pack two floats into a half2 bit pattern
__device__ __forceinline__ uint pack_h2f(float a, float b) {
  half_t ha = (half_t)a, hb = (half_t)b;
  unsigned short ua = __builtin_bit_cast(unsigned short, ha);
  unsigned short ub = __builtin_bit_cast(unsigned short, hb);
  return (uint)ua | ((uint)ub << 16);
}

// acc += silu*bw + sum_g basis[g]*w[g]   (fp16 dot2 pairs, fp32 accumulate)
// Weights pass BY VALUE (uint4 + uint) from uniform compile-time offsets of
// global W -> CSE'd s_load into SGPRs (scalar path, off the VALU/LDS pipes).
__device__ __forceinline__ float dot8v(uint d0, uint d1, uint d2, uint d3,
                                       float sv, uint4 wa, uint wb, float acc) {
  acc = fmaf(sv, __uint_as_float(wb), acc);
#if __has_builtin(__builtin_amdgcn_fdot2)
  acc = __builtin_amdgcn_fdot2(__builtin_bit_cast(h2, d0), __builtin_bit_cast(h2, wa.x), acc, false);
  acc = __builtin_amdgcn_fdot2(__builtin_bit_cast(h2, d1), __builtin_bit_cast(h2, wa.y), acc, false);
  acc = __builtin_amdgcn_fdot2(__builtin_bit_cast(h2, d2), __builtin_bit_cast(h2, wa.z), acc, false);
  acc = __builtin_amdgcn_fdot2(__builtin_bit_cast(h2, d3), __builtin_bit_cast(h2, wa.w), acc, false);
#else
  uint dd[4] = {d0, d1, d2, d3};
  uint ww[4] = {wa.x, wa.y, wa.z, wa.w};
#pragma unroll
  for (int k = 0; k < 4; ++k) {
    h2 f = __builtin_bit_cast(h2, dd[k]);
    h2 wv = __builtin_bit_cast(h2, ww[k]);
    acc = fmaf((float)f.x, (float)wv.x, acc);
    acc = fmaf((float)f.y, (float)wv.y, acc);
  }
#endif
  return acc;
}

// Uniform-knot cubic B-spline + silu features -> registers.
// d0,d1 = basis halves 0..3; d2,d3 = halves 4..7; sv = silu (f32).
__device__ __forceinline__ void feat_reg(float x, uint& d0, uint& d1,
                                         uint& d2, uint& d3, float& sv) {
  float e = __expf(-x);
  sv = x * __builtin_amdgcn_rcpf(1.0f + e);
  float s = fmaf(x, 2.5f, 5.5f);       // (x - (-2.2)) / 0.4
  float sf = floorf(s);
  float t = s - sf;
  int p = (int)sf - 3;                 // first nonzero basis index (may be <0)
  float omt = 1.0f - t, t2 = t * t;
  float B0 = (1.0f / 6.0f) * omt * omt * omt;
  float B3 = (1.0f / 6.0f) * t2 * t;
  float B1 = fmaf(0.5f * t, t2, 2.0f / 3.0f - t2);
  float B2 = 1.0f - B0 - B1 - B3;      // partition of unity
  u64 Av = ((u64)pack_h2f(B2, B3) << 32) | pack_h2f(B0, B1);
  int n = p < 0 ? -p : 0;              // halves below 0: pre-drop
  Av = (n >= 4) ? 0ull : (Av >> (16 * n));
  int pc = p < 0 ? 0 : (p > 9 ? 9 : p);
  int sh = 16 * pc;                    // 0..144
  u64 lo = (sh < 64) ? (Av << sh) : 0ull;
  u64 hi = (sh == 0) ? 0ull
         : (sh < 64) ? (Av >> (64 - sh))
         : (sh < 128) ? (Av << (sh - 64)) : 0ull;
  d0 = (uint)lo; d1 = (uint)(lo >> 32);
  d2 = (uint)hi; d3 = (uint)(hi >> 32);
}

// feat -> SoA LDS slot (used only for the small F2 map now)
__device__ __forceinline__ void feat_store(float x, uint* __restrict__ A,
                                           uint* __restrict__ Bq,
                                           uint* __restrict__ S) {
  uint d0, d1, d2, d3; float sv;
  feat_reg(x, d0, d1, d2, d3, sv);
  *(uint2*)A = make_uint2(d0, d1);
  *(uint2*)Bq = make_uint2(d2, d3);
  *S = __float_as_uint(sv);
}

// Packed fp16 weights in d_ws, 8-dword (32 B) aligned entries:
//   entry t       (t=0..17):  layer 1, t = o*9+tap
//   entry 18+q    (q=0..35):  layer 2, q = wid*9+tap, wid = o*2+ci
//   dwords 0..3 = 4x half2 spline weights (*scaler), dword 4 = f32 base_w
__global__ void pack_w(const float* __restrict__ bw1, const float* __restrict__ sw1,
                       const float* __restrict__ sc1, const float* __restrict__ bw2,
                       const float* __restrict__ sw2, const float* __restrict__ sc2,
                       uint* __restrict__ W) {
  const int t = threadIdx.x;
  if (t < 18) {
    const float scv = sc1[t];
    uint* dst = W + t * 8;
#pragma unroll
    for (int j = 0; j < 4; ++j)
      dst[j] = pack_h2f(sw1[t * 8 + 2 * j] * scv, sw1[t * 8 + 2 * j + 1] * scv);
    dst[4] = __float_as_uint(bw1[t]);
  } else if (t < 54) {
    const int q = t - 18;
    const float scv = sc2[q];
    uint* dst = W + t * 8;
#pragma unroll
    for (int j = 0; j < 4; ++j)
      dst[j] = pack_h2f(sw2[q * 8 + 2 * j] * scv, sw2[q * 8 + 2 * j + 1] * scv);
    dst[4] = __float_as_uint(bw2[q]);
  }
}

// R11: fully-fused layer 1. Each thread (one 2x2 pool quad) loads its 4x4
// input window from global (L1-resident, 3 KB/block) and computes the 16
// feature vectors IN REGISTERS — no F1 LDS staging, no stage-1 barrier.
// LDS shrinks 25.8 KB -> 10.7 KB: 8 blocks/CU = 32 waves = 100% occupancy
// (VGPR capped at 64 via launch_bounds min-waves 8; est. live set ~50).
// LDS layout (dwords), F2 parity-split columns (col c at (c>>1)+(c&1)*7):
//   F2A [0,784)      392 x uint2   halves 0..3
//   F2B [784,1568)   392 x uint2   halves 4..7
//   F2S [1568,1960)  392 x f32     silu
//   P   [1960,2744)  4*49*4 f32    stage-3 partials
__global__ __launch_bounds__(TPB, 8) void kan_fwd(
    const float* __restrict__ x, const uint* __restrict__ W,
    float* __restrict__ out)
{
  __shared__ __align__(16) uint lds[2744];  // 10.7 KB
  uint* F2A = lds;
  uint* F2B = lds + 784;
  uint* F2S = lds + 1568;
  float* P = (float*)(lds + 1960);

  const int tid = threadIdx.x;
  const float* xb = x + (size_t)blockIdx.x * 784;

  // ---- Fused stage 1+2: layer-1 conv + pool + F2 features ----
  if (tid < 196) {
    const int ph = tid / 14, pw = tid % 14;
    // load the 4x4 input window (padded coords row/col in [-1,28])
    float xv[16];
#pragma unroll
    for (int r = 0; r < 4; ++r) {
      const int row = 2 * ph + r - 1;
#pragma unroll
      for (int c = 0; c < 4; ++c) {
        const int col = 2 * pw + c - 1;
        const bool ok = ((uint)row < 28u) && ((uint)col < 28u);
        const int xi = min(max(row, 0), 27) * 28 + min(max(col, 0), 27);
        float v = xb[xi];
        xv[r * 4 + c] = ok ? v : 0.0f;   // padding pixels: x = 0
      }
    }
    float acc[2][4];
#pragma unroll
    for (int o = 0; o < 2; ++o)
#pragma unroll
      for (int q = 0; q < 4; ++q) acc[o][q] = 0.0f;
#pragma unroll
    for (int r = 0; r < 4; ++r) {
#pragma unroll
      for (int c = 0; c < 4; ++c) {
        uint d0, d1, d2, d3; float sv;
        feat_reg(xv[r * 4 + c], d0, d1, d2, d3, sv);
#pragma unroll
        for (int dh = 0; dh < 2; ++dh) {
          if (r - dh < 0 || r - dh > 2) continue;
#pragma unroll
          for (int dw = 0; dw < 2; ++dw) {
            if (c - dw < 0 || c - dw > 2) continue;
            const int tap = (r - dh) * 3 + (c - dw);
#pragma unroll
            for (int o = 0; o < 2; ++o) {
              const uint4 wa = *(const uint4*)(W + (o * 9 + tap) * 8);
              const uint wb = W[(o * 9 + tap) * 8 + 4];
              acc[o][dh * 2 + dw] =
                  dot8v(d0, d1, d2, d3, sv, wa, wb, acc[o][dh * 2 + dw]);
            }
          }
        }
      }
    }
#pragma unroll
    for (int o = 0; o < 2; ++o) {
      float m = fmaxf(fmaxf(acc[o][0], acc[o][1]), fmaxf(acc[o][2], acc[o][3]));
      int fidx = o * 196 + ph * 14 + (pw >> 1) + (pw & 1) * 7;
      feat_store(m, F2A + fidx * 2, F2B + fidx * 2, F2S + fidx);
    }
  }
  __syncthreads();

  // ---- Stage 3: layer-2 conv; one wave per (o,ci), lane = 7x7 pool pos ----
  {
    const int wid = __builtin_amdgcn_readfirstlane(tid >> 6);  // = o*2+ci
    const int lane = tid & 63;
    // features of x=0 (padding): basis halves 2..5 = {1/48, 23/48, 23/48, 1/48}
    const uint F0d1 = pack_h2f(1.0f / 48.0f, 23.0f / 48.0f);
    const uint F0d2 = pack_h2f(23.0f / 48.0f, 1.0f / 48.0f);
    if (lane < 49) {
      const int ci = wid & 1;
      const int ph = lane / 7, pw = lane % 7;
      float pa[4] = {0.0f, 0.0f, 0.0f, 0.0f};
#pragma unroll
      for (int r = 0; r < 4; ++r) {
#pragma unroll
        for (int c = 0; c < 4; ++c) {
          int row = 2 * ph + r - 1, col = 2 * pw + c - 1;
          bool ok = ((uint)row < 14u) && ((uint)col < 14u);
          int rcl = min(max(row, 0), 13), ccl = min(max(col, 0), 13);
          const int fidx = ci * 196 + rcl * 14 + (ccl >> 1) + (ccl & 1) * 7;
          uint2 a = *(const uint2*)(F2A + fidx * 2);
          uint2 bq = *(const uint2*)(F2B + fidx * 2);
          float sv = ok ? __uint_as_float(F2S[fidx]) : 0.0f;
          uint d0 = ok ? a.x : 0u;
          uint d1 = ok ? a.y : F0d1;
          uint d2 = ok ? bq.x : F0d2;
          uint d3 = ok ? bq.y : 0u;
#pragma unroll
          for (int dh = 0; dh < 2; ++dh) {
            if (r - dh < 0 || r - dh > 2) continue;
#pragma unroll
            for (int dw = 0; dw < 2; ++dw) {
              if (c - dw < 0 || c - dw > 2) continue;
              const int tap = (r - dh) * 3 + (c - dw);
              const uint4 wa = *(const uint4*)(W + (18 + wid * 9 + tap) * 8);
              const uint wb = W[(18 + wid * 9 + tap) * 8 + 4];
              pa[dh * 2 + dw] =
                  dot8v(d0, d1, d2, d3, sv, wa, wb, pa[dh * 2 + dw]);
            }
          }
        }
      }
      *(float4*)&P[(wid * 49 + lane) * 4] = make_float4(pa[0], pa[1], pa[2], pa[3]);
    }
  }
  __syncthreads();

  // ---- Stage 4: sum input channels, 2x2 maxpool, write (2,7,7) flat ----
  if (tid < 98) {
    const int o = tid / 49, pos = tid % 49;
    const float4 p0 = *(const float4*)&P[((o * 2 + 0) * 49 + pos) * 4];
    const float4 p1 = *(const float4*)&P[((o * 2 + 1) * 49 + pos) * 4];
    float m = fmaxf(fmaxf(p0.x + p1.x, p0.y + p1.y), fmaxf(p0.z + p1.z, p0.w + p1.w));
    out[(size_t)blockIdx.x * 98 + tid] = m;
  }
}

extern "C" void kernel_launch(void* const* d_in, const int* in_sizes, int n_in,
                              void* d_out, int out_size, void* d_ws, size_t ws_size,
                              hipStream_t stream) {
  const float* x   = (const float*)d_in[0];
  const float* bw1 = (const float*)d_in[1];
  const float* sw1 = (const float*)d_in[2];
  const float* sc1 = (const float*)d_in[3];
  const float* bw2 = (const float*)d_in[4];
  const float* sw2 = (const float*)d_in[5];
  const float* sc2 = (const float*)d_in[6];
  float* out = (float*)d_out;
  uint* W = (uint*)d_ws;  // 432 dwords (54 entries x 8)
  const int B = in_sizes[0] / 784;  // 2048
  pack_w<<<1, 64, 0, stream>>>(bw1, sw1, sc1, bw2, sw2, sc2, W);
  kan_fwd<<<B, TPB, 0, stream>>>(x, W, out);
}

// Round 5
// 123.430 us; speedup vs baseline: 1.4765x; 1.4765x over previous
//
#include <hip/hip_runtime.h>
#include <math.h>

typedef _Float16 half_t;
typedef _Float16 h2 __attribute__((ext_vector_type(2)));
typedef unsigned int uint;
typedef unsigned long long u64;

#define TPB 256

// pack two floats into a half2 bit pattern
__device__ __forceinline__ uint pack_h2f(float a, float b) {
  half_t ha = (half_t)a, hb = (half_t)b;
  unsigned short ua = __builtin_bit_cast(unsigned short, ha);
  unsigned short ub = __builtin_bit_cast(unsigned short, hb);
  return (uint)ua | ((uint)ub << 16);
}

// acc += silu*bw + sum_g basis[g]*w[g]   (fp16 dot2 pairs, fp32 accumulate)
// Weights pass BY VALUE (uint4 + uint) from uniform compile-time offsets of
// global W -> CSE'd s_load into SGPRs (scalar path, off the VALU/LDS pipes).
__device__ __forceinline__ float dot8v(uint d0, uint d1, uint d2, uint d3,
                                       float sv, uint4 wa, uint wb, float acc) {
  acc = fmaf(sv, __uint_as_float(wb), acc);
#if __has_builtin(__builtin_amdgcn_fdot2)
  acc = __builtin_amdgcn_fdot2(__builtin_bit_cast(h2, d0), __builtin_bit_cast(h2, wa.x), acc, false);
  acc = __builtin_amdgcn_fdot2(__builtin_bit_cast(h2, d1), __builtin_bit_cast(h2, wa.y), acc, false);
  acc = __builtin_amdgcn_fdot2(__builtin_bit_cast(h2, d2), __builtin_bit_cast(h2, wa.z), acc, false);
  acc = __builtin_amdgcn_fdot2(__builtin_bit_cast(h2, d3), __builtin_bit_cast(h2, wa.w), acc, false);
#else
  uint dd[4] = {d0, d1, d2, d3};
  uint ww[4] = {wa.x, wa.y, wa.z, wa.w};
#pragma unroll
  for (int k = 0; k < 4; ++k) {
    h2 f = __builtin_bit_cast(h2, dd[k]);
    h2 wv = __builtin_bit_cast(h2, ww[k]);
    acc = fmaf((float)f.x, (float)wv.x, acc);
    acc = fmaf((float)f.y, (float)wv.y, acc);
  }
#endif
  return acc;
}

// Uniform-knot cubic B-spline + silu features -> registers.
// d0,d1 = basis halves 0..3; d2,d3 = halves 4..7; sv = silu (f32).
__device__ __forceinline__ void feat_reg(float x, uint& d0, uint& d1,
                                         uint& d2, uint& d3, float& sv) {
  float e = __expf(-x);
  sv = x * __builtin_amdgcn_rcpf(1.0f + e);
  float s = fmaf(x, 2.5f, 5.5f);       // (x - (-2.2)) / 0.4
  float sf = floorf(s);
  float t = s - sf;
  int p = (int)sf - 3;                 // first nonzero basis index (may be <0)
  float omt = 1.0f - t, t2 = t * t;
  float B0 = (1.0f / 6.0f) * omt * omt * omt;
  float B3 = (1.0f / 6.0f) * t2 * t;
  float B1 = fmaf(0.5f * t, t2, 2.0f / 3.0f - t2);
  float B2 = 1.0f - B0 - B1 - B3;      // partition of unity
  u64 Av = ((u64)pack_h2f(B2, B3) << 32) | pack_h2f(B0, B1);
  int n = p < 0 ? -p : 0;              // halves below 0: pre-drop
  Av = (n >= 4) ? 0ull : (Av >> (16 * n));
  int pc = p < 0 ? 0 : (p > 9 ? 9 : p);
  int sh = 16 * pc;                    // 0..144
  u64 lo = (sh < 64) ? (Av << sh) : 0ull;
  u64 hi = (sh == 0) ? 0ull
         : (sh < 64) ? (Av >> (64 - sh))
         : (sh < 128) ? (Av << (sh - 64)) : 0ull;
  d0 = (uint)lo; d1 = (uint)(lo >> 32);
  d2 = (uint)hi; d3 = (uint)(hi >> 32);
}

// feat -> SoA LDS slot (used only for the small F2 map)
__device__ __forceinline__ void feat_store(float x, uint* __restrict__ A,
                                           uint* __restrict__ Bq,
                                           uint* __restrict__ S) {
  uint d0, d1, d2, d3; float sv;
  feat_reg(x, d0, d1, d2, d3, sv);
  *(uint2*)A = make_uint2(d0, d1);
  *(uint2*)Bq = make_uint2(d2, d3);
  *S = __float_as_uint(sv);
}

// Packed fp16 weights in d_ws, 8-dword (32 B) aligned entries:
//   entry t       (t=0..17):  layer 1, t = o*9+tap
//   entry 18+q    (q=0..35):  layer 2, q = wid*9+tap, wid = o*2+ci
//   dwords 0..3 = 4x half2 spline weights (*scaler), dword 4 = f32 base_w
__global__ void pack_w(const float* __restrict__ bw1, const float* __restrict__ sw1,
                       const float* __restrict__ sc1, const float* __restrict__ bw2,
                       const float* __restrict__ sw2, const float* __restrict__ sc2,
                       uint* __restrict__ W) {
  const int t = threadIdx.x;
  if (t < 18) {
    const float scv = sc1[t];
    uint* dst = W + t * 8;
#pragma unroll
    for (int j = 0; j < 4; ++j)
      dst[j] = pack_h2f(sw1[t * 8 + 2 * j] * scv, sw1[t * 8 + 2 * j + 1] * scv);
    dst[4] = __float_as_uint(bw1[t]);
  } else if (t < 54) {
    const int q = t - 18;
    const float scv = sc2[q];
    uint* dst = W + t * 8;
#pragma unroll
    for (int j = 0; j < 4; ++j)
      dst[j] = pack_h2f(sw2[q * 8 + 2 * j] * scv, sw2[q * 8 + 2 * j + 1] * scv);
    dst[4] = __float_as_uint(bw2[q]);
  }
}

// R12: same fused structure as R11 (layer-1 features in registers, no F1 LDS,
// two barriers total), but launch_bounds min-waves relaxed 8 -> 6.
// R4 evidence: min-waves=8 forced VGPR_Count=32 (< ~50 live set) -> 317 MB/
// dispatch scratch traffic, 116 us. Cap at 6 gives ~85-VGPR budget; natural
// demand ~60 -> no spill, and runtime occupancy can still reach 8 blocks/CU
// if allocation lands <= 64 VGPRs.
// LDS layout (dwords), F2 parity-split columns (col c at (c>>1)+(c&1)*7):
//   F2A [0,784)      392 x uint2   halves 0..3
//   F2B [784,1568)   392 x uint2   halves 4..7
//   F2S [1568,1960)  392 x f32     silu
//   P   [1960,2744)  4*49*4 f32    stage-3 partials
__global__ __launch_bounds__(TPB, 6) void kan_fwd(
    const float* __restrict__ x, const uint* __restrict__ W,
    float* __restrict__ out)
{
  __shared__ __align__(16) uint lds[2744];  // 10.7 KB
  uint* F2A = lds;
  uint* F2B = lds + 784;
  uint* F2S = lds + 1568;
  float* P = (float*)(lds + 1960);

  const int tid = threadIdx.x;
  const float* xb = x + (size_t)blockIdx.x * 784;

  // ---- Fused stage 1+2: layer-1 conv + pool + F2 features ----
  if (tid < 196) {
    const int ph = tid / 14, pw = tid % 14;
    // load the 4x4 input window (padded coords row/col in [-1,28])
    float xv[16];
#pragma unroll
    for (int r = 0; r < 4; ++r) {
      const int row = 2 * ph + r - 1;
#pragma unroll
      for (int c = 0; c < 4; ++c) {
        const int col = 2 * pw + c - 1;
        const bool ok = ((uint)row < 28u) && ((uint)col < 28u);
        const int xi = min(max(row, 0), 27) * 28 + min(max(col, 0), 27);
        float v = xb[xi];
        xv[r * 4 + c] = ok ? v : 0.0f;   // padding pixels: x = 0
      }
    }
    float acc[2][4];
#pragma unroll
    for (int o = 0; o < 2; ++o)
#pragma unroll
      for (int q = 0; q < 4; ++q) acc[o][q] = 0.0f;
#pragma unroll
    for (int r = 0; r < 4; ++r) {
#pragma unroll
      for (int c = 0; c < 4; ++c) {
        uint d0, d1, d2, d3; float sv;
        feat_reg(xv[r * 4 + c], d0, d1, d2, d3, sv);
#pragma unroll
        for (int dh = 0; dh < 2; ++dh) {
          if (r - dh < 0 || r - dh > 2) continue;
#pragma unroll
          for (int dw = 0; dw < 2; ++dw) {
            if (c - dw < 0 || c - dw > 2) continue;
            const int tap = (r - dh) * 3 + (c - dw);
#pragma unroll
            for (int o = 0; o < 2; ++o) {
              const uint4 wa = *(const uint4*)(W + (o * 9 + tap) * 8);
              const uint wb = W[(o * 9 + tap) * 8 + 4];
              acc[o][dh * 2 + dw] =
                  dot8v(d0, d1, d2, d3, sv, wa, wb, acc[o][dh * 2 + dw]);
            }
          }
        }
      }
    }
#pragma unroll
    for (int o = 0; o < 2; ++o) {
      float m = fmaxf(fmaxf(acc[o][0], acc[o][1]), fmaxf(acc[o][2], acc[o][3]));
      int fidx = o * 196 + ph * 14 + (pw >> 1) + (pw & 1) * 7;
      feat_store(m, F2A + fidx * 2, F2B + fidx * 2, F2S + fidx);
    }
  }
  __syncthreads();

  // ---- Stage 3: layer-2 conv; one wave per (o,ci), lane = 7x7 pool pos ----
  {
    const int wid = __builtin_amdgcn_readfirstlane(tid >> 6);  // = o*2+ci
    const int lane = tid & 63;
    // features of x=0 (padding): basis halves 2..5 = {1/48, 23/48, 23/48, 1/48}
    const uint F0d1 = pack_h2f(1.0f / 48.0f, 23.0f / 48.0f);
    const uint F0d2 = pack_h2f(23.0f / 48.0f, 1.0f / 48.0f);
    if (lane < 49) {
      const int ci = wid & 1;
      const int ph = lane / 7, pw = lane % 7;
      float pa[4] = {0.0f, 0.0f, 0.0f, 0.0f};
#pragma unroll
      for (int r = 0; r < 4; ++r) {
#pragma unroll
        for (int c = 0; c < 4; ++c) {
          int row = 2 * ph + r - 1, col = 2 * pw + c - 1;
          bool ok = ((uint)row < 14u) && ((uint)col < 14u);
          int rcl = min(max(row, 0), 13), ccl = min(max(col, 0), 13);
          const int fidx = ci * 196 + rcl * 14 + (ccl >> 1) + (ccl & 1) * 7;
          uint2 a = *(const uint2*)(F2A + fidx * 2);
          uint2 bq = *(const uint2*)(F2B + fidx * 2);
          float sv = ok ? __uint_as_float(F2S[fidx]) : 0.0f;
          uint d0 = ok ? a.x : 0u;
          uint d1 = ok ? a.y : F0d1;
          uint d2 = ok ? bq.x : F0d2;
          uint d3 = ok ? bq.y : 0u;
#pragma unroll
          for (int dh = 0; dh < 2; ++dh) {
            if (r - dh < 0 || r - dh > 2) continue;
#pragma unroll
            for (int dw = 0; dw < 2; ++dw) {
              if (c - dw < 0 || c - dw > 2) continue;
              const int tap = (r - dh) * 3 + (c - dw);
              const uint4 wa = *(const uint4*)(W + (18 + wid * 9 + tap) * 8);
              const uint wb = W[(18 + wid * 9 + tap) * 8 + 4];
              pa[dh * 2 + dw] =
                  dot8v(d0, d1, d2, d3, sv, wa, wb, pa[dh * 2 + dw]);
            }
          }
        }
      }
      *(float4*)&P[(wid * 49 + lane) * 4] = make_float4(pa[0], pa[1], pa[2], pa[3]);
    }
  }
  __syncthreads();

  // ---- Stage 4: sum input channels, 2x2 maxpool, write (2,7,7) flat ----
  if (tid < 98) {
    const int o = tid / 49, pos = tid % 49;
    const float4 p0 = *(const float4*)&P[((o * 2 + 0) * 49 + pos) * 4];
    const float4 p1 = *(const float4*)&P[((o * 2 + 1) * 49 + pos) * 4];
    float m = fmaxf(fmaxf(p0.x + p1.x, p0.y + p1.y), fmaxf(p0.z + p1.z, p0.w + p1.w));
    out[(size_t)blockIdx.x * 98 + tid] = m;
  }
}

extern "C" void kernel_launch(void* const* d_in, const int* in_sizes, int n_in,
                              void* d_out, int out_size, void* d_ws, size_t ws_size,
                              hipStream_t stream) {
  const float* x   = (const float*)d_in[0];
  const float* bw1 = (const float*)d_in[1];
  const float* sw1 = (const float*)d_in[2];
  const float* sc1 = (const float*)d_in[3];
  const float* bw2 = (const float*)d_in[4];
  const float* sw2 = (const float*)d_in[5];
  const float* sc2 = (const float*)d_in[6];
  float* out = (float*)d_out;
  uint* W = (uint*)d_ws;  // 432 dwords (54 entries x 8)
  const int B = in_sizes[0] / 784;  // 2048
  pack_w<<<1, 64, 0, stream>>>(bw1, sw1, sc1, bw2, sw2, sc2, W);
  kan_fwd<<<B, TPB, 0, stream>>>(x, W, out);
}

// Round 6
// 97.913 us; speedup vs baseline: 1.8613x; 1.2606x over previous
//
#include <hip/hip_runtime.h>
#include <math.h>

typedef _Float16 half_t;
typedef _Float16 h2 __attribute__((ext_vector_type(2)));
typedef unsigned int uint;
typedef unsigned long long u64;

#define TPB 256

// pack two floats into a half2 bit pattern
__device__ __forceinline__ uint pack_h2f(float a, float b) {
  half_t ha = (half_t)a, hb = (half_t)b;
  unsigned short ua = __builtin_bit_cast(unsigned short, ha);
  unsigned short ub = __builtin_bit_cast(unsigned short, hb);
  return (uint)ua | ((uint)ub << 16);
}

// acc += silu*bw + sum_g basis[g]*w[g]   (fp16 dot2 pairs, fp32 accumulate)
// Weights pass BY VALUE (uint4 + uint) from uniform offsets of global W ->
// CSE'd s_load into SGPRs (scalar path, off the VALU/LDS pipes).
__device__ __forceinline__ float dot8v(uint d0, uint d1, uint d2, uint d3,
                                       float sv, uint4 wa, uint wb, float acc) {
  acc = fmaf(sv, __uint_as_float(wb), acc);
#if __has_builtin(__builtin_amdgcn_fdot2)
  acc = __builtin_amdgcn_fdot2(__builtin_bit_cast(h2, d0), __builtin_bit_cast(h2, wa.x), acc, false);
  acc = __builtin_amdgcn_fdot2(__builtin_bit_cast(h2, d1), __builtin_bit_cast(h2, wa.y), acc, false);
  acc = __builtin_amdgcn_fdot2(__builtin_bit_cast(h2, d2), __builtin_bit_cast(h2, wa.z), acc, false);
  acc = __builtin_amdgcn_fdot2(__builtin_bit_cast(h2, d3), __builtin_bit_cast(h2, wa.w), acc, false);
#else
  uint dd[4] = {d0, d1, d2, d3};
  uint ww[4] = {wa.x, wa.y, wa.z, wa.w};
#pragma unroll
  for (int k = 0; k < 4; ++k) {
    h2 f = __builtin_bit_cast(h2, dd[k]);
    h2 wv = __builtin_bit_cast(h2, ww[k]);
    acc = fmaf((float)f.x, (float)wv.x, acc);
    acc = fmaf((float)f.y, (float)wv.y, acc);
  }
#endif
  return acc;
}

// Uniform-knot cubic B-spline + silu features -> registers.
__device__ __forceinline__ void feat_reg(float x, uint& d0, uint& d1,
                                         uint& d2, uint& d3, float& sv) {
  float e = __expf(-x);
  sv = x * __builtin_amdgcn_rcpf(1.0f + e);
  float s = fmaf(x, 2.5f, 5.5f);       // (x - (-2.2)) / 0.4
  float sf = floorf(s);
  float t = s - sf;
  int p = (int)sf - 3;                 // first nonzero basis index (may be <0)
  float omt = 1.0f - t, t2 = t * t;
  float B0 = (1.0f / 6.0f) * omt * omt * omt;
  float B3 = (1.0f / 6.0f) * t2 * t;
  float B1 = fmaf(0.5f * t, t2, 2.0f / 3.0f - t2);
  float B2 = 1.0f - B0 - B1 - B3;      // partition of unity
  u64 Av = ((u64)pack_h2f(B2, B3) << 32) | pack_h2f(B0, B1);
  int n = p < 0 ? -p : 0;              // halves below 0: pre-drop
  Av = (n >= 4) ? 0ull : (Av >> (16 * n));
  int pc = p < 0 ? 0 : (p > 9 ? 9 : p);
  int sh = 16 * pc;                    // 0..144
  u64 lo = (sh < 64) ? (Av << sh) : 0ull;
  u64 hi = (sh == 0) ? 0ull
         : (sh < 64) ? (Av >> (64 - sh))
         : (sh < 128) ? (Av << (sh - 64)) : 0ull;
  d0 = (uint)lo; d1 = (uint)(lo >> 32);
  d2 = (uint)hi; d3 = (uint)(hi >> 32);
}

// feat -> SoA LDS slot (used only for the small F2 map)
__device__ __forceinline__ void feat_store(float x, uint* __restrict__ A,
                                           uint* __restrict__ Bq,
                                           uint* __restrict__ S) {
  uint d0, d1, d2, d3; float sv;
  feat_reg(x, d0, d1, d2, d3, sv);
  *(uint2*)A = make_uint2(d0, d1);
  *(uint2*)Bq = make_uint2(d2, d3);
  *S = __float_as_uint(sv);
}

// Packed fp16 weights in d_ws, 8-dword (32 B) aligned entries:
//   entry t       (t=0..17):  layer 1, t = o*9+tap
//   entry 18+q    (q=0..35):  layer 2, q = wid*9+tap, wid = o*2+ci
//   dwords 0..3 = 4x half2 spline weights (*scaler), dword 4 = f32 base_w
__global__ void pack_w(const float* __restrict__ bw1, const float* __restrict__ sw1,
                       const float* __restrict__ sc1, const float* __restrict__ bw2,
                       const float* __restrict__ sw2, const float* __restrict__ sc2,
                       uint* __restrict__ W) {
  const int t = threadIdx.x;
  if (t < 18) {
    const float scv = sc1[t];
    uint* dst = W + t * 8;
#pragma unroll
    for (int j = 0; j < 4; ++j)
      dst[j] = pack_h2f(sw1[t * 8 + 2 * j] * scv, sw1[t * 8 + 2 * j + 1] * scv);
    dst[4] = __float_as_uint(bw1[t]);
  } else if (t < 54) {
    const int q = t - 18;
    const float scv = sc2[q];
    uint* dst = W + t * 8;
#pragma unroll
    for (int j = 0; j < 4; ++j)
      dst[j] = pack_h2f(sw2[q * 8 + 2 * j] * scv, sw2[q * 8 + 2 * j + 1] * scv);
    dst[4] = __float_as_uint(bw2[q]);
  }
}

// R13: fused layer-1 (features in registers, no F1 LDS), with the VGPR-cap
// rule discovered over R4/R5/R9: hipcc caps arch-VGPRs at ~floor(256/minwaves)
// (granule 8): w=5->48, w=6->40, w=8->32. So the previous bounds STARVED the
// kernel (demand ~76 > cap 40 -> 113 MB/dispatch scratch). Fix:
//   (a) launch_bounds(256,4) -> cap 64; <=64 VGPRs still allows 32 waves/CU.
//   (b) no xv[16] buffer: load each pixel inside the loop (-16 regs demand).
// LDS layout (dwords), F2 parity-split columns (col c at (c>>1)+(c&1)*7):
//   F2A [0,784)      392 x uint2   halves 0..3
//   F2B [784,1568)   392 x uint2   halves 4..7
//   F2S [1568,1960)  392 x f32     silu
//   P   [1960,2744)  4*49*4 f32    stage-3 partials
__global__ __launch_bounds__(TPB, 4) void kan_fwd(
    const float* __restrict__ x, const uint* __restrict__ W,
    float* __restrict__ out)
{
  __shared__ __align__(16) uint lds[2744];  // 10.7 KB
  uint* F2A = lds;
  uint* F2B = lds + 784;
  uint* F2S = lds + 1568;
  float* P = (float*)(lds + 1960);

  const int tid = threadIdx.x;
  const float* xb = x + (size_t)blockIdx.x * 784;

  // ---- Fused stage 1+2: layer-1 conv + pool + F2 features ----
  if (tid < 196) {
    const int ph = tid / 14, pw = tid % 14;
    float acc[2][4];
#pragma unroll
    for (int o = 0; o < 2; ++o)
#pragma unroll
      for (int q = 0; q < 4; ++q) acc[o][q] = 0.0f;
#pragma unroll
    for (int r = 0; r < 4; ++r) {
      const int row = 2 * ph + r - 1;
#pragma unroll
      for (int c = 0; c < 4; ++c) {
        const int col = 2 * pw + c - 1;
        const bool ok = ((uint)row < 28u) && ((uint)col < 28u);
        const int xi = min(max(row, 0), 27) * 28 + min(max(col, 0), 27);
        float v = xb[xi];
        const float xval = ok ? v : 0.0f;   // padding pixels: x = 0
        uint d0, d1, d2, d3; float sv;
        feat_reg(xval, d0, d1, d2, d3, sv);
#pragma unroll
        for (int dh = 0; dh < 2; ++dh) {
          if (r - dh < 0 || r - dh > 2) continue;
#pragma unroll
          for (int dw = 0; dw < 2; ++dw) {
            if (c - dw < 0 || c - dw > 2) continue;
            const int tap = (r - dh) * 3 + (c - dw);
#pragma unroll
            for (int o = 0; o < 2; ++o) {
              const uint4 wa = *(const uint4*)(W + (o * 9 + tap) * 8);
              const uint wb = W[(o * 9 + tap) * 8 + 4];
              acc[o][dh * 2 + dw] =
                  dot8v(d0, d1, d2, d3, sv, wa, wb, acc[o][dh * 2 + dw]);
            }
          }
        }
      }
    }
#pragma unroll
    for (int o = 0; o < 2; ++o) {
      float m = fmaxf(fmaxf(acc[o][0], acc[o][1]), fmaxf(acc[o][2], acc[o][3]));
      int fidx = o * 196 + ph * 14 + (pw >> 1) + (pw & 1) * 7;
      feat_store(m, F2A + fidx * 2, F2B + fidx * 2, F2S + fidx);
    }
  }
  __syncthreads();

  // ---- Stage 3: layer-2 conv; one wave per (o,ci), lane = 7x7 pool pos ----
  {
    const int wid = __builtin_amdgcn_readfirstlane(tid >> 6);  // = o*2+ci
    const int lane = tid & 63;
    // features of x=0 (padding): basis halves 2..5 = {1/48, 23/48, 23/48, 1/48}
    const uint F0d1 = pack_h2f(1.0f / 48.0f, 23.0f / 48.0f);
    const uint F0d2 = pack_h2f(23.0f / 48.0f, 1.0f / 48.0f);
    if (lane < 49) {
      const int ci = wid & 1;
      const int ph = lane / 7, pw = lane % 7;
      float pa[4] = {0.0f, 0.0f, 0.0f, 0.0f};
#pragma unroll
      for (int r = 0; r < 4; ++r) {
#pragma unroll
        for (int c = 0; c < 4; ++c) {
          int row = 2 * ph + r - 1, col = 2 * pw + c - 1;
          bool ok = ((uint)row < 14u) && ((uint)col < 14u);
          int rcl = min(max(row, 0), 13), ccl = min(max(col, 0), 13);
          const int fidx = ci * 196 + rcl * 14 + (ccl >> 1) + (ccl & 1) * 7;
          uint2 a = *(const uint2*)(F2A + fidx * 2);
          uint2 bq = *(const uint2*)(F2B + fidx * 2);
          float sv = ok ? __uint_as_float(F2S[fidx]) : 0.0f;
          uint d0 = ok ? a.x : 0u;
          uint d1 = ok ? a.y : F0d1;
          uint d2 = ok ? bq.x : F0d2;
          uint d3 = ok ? bq.y : 0u;
#pragma unroll
          for (int dh = 0; dh < 2; ++dh) {
            if (r - dh < 0 || r - dh > 2) continue;
#pragma unroll
            for (int dw = 0; dw < 2; ++dw) {
              if (c - dw < 0 || c - dw > 2) continue;
              const int tap = (r - dh) * 3 + (c - dw);
              const uint4 wa = *(const uint4*)(W + (18 + wid * 9 + tap) * 8);
              const uint wb = W[(18 + wid * 9 + tap) * 8 + 4];
              pa[dh * 2 + dw] =
                  dot8v(d0, d1, d2, d3, sv, wa, wb, pa[dh * 2 + dw]);
            }
          }
        }
      }
      *(float4*)&P[(wid * 49 + lane) * 4] = make_float4(pa[0], pa[1], pa[2], pa[3]);
    }
  }
  __syncthreads();

  // ---- Stage 4: sum input channels, 2x2 maxpool, write (2,7,7) flat ----
  if (tid < 98) {
    const int o = tid / 49, pos = tid % 49;
    const float4 p0 = *(const float4*)&P[((o * 2 + 0) * 49 + pos) * 4];
    const float4 p1 = *(const float4*)&P[((o * 2 + 1) * 49 + pos) * 4];
    float m = fmaxf(fmaxf(p0.x + p1.x, p0.y + p1.y), fmaxf(p0.z + p1.z, p0.w + p1.w));
    out[(size_t)blockIdx.x * 98 + tid] = m;
  }
}

extern "C" void kernel_launch(void* const* d_in, const int* in_sizes, int n_in,
                              void* d_out, int out_size, void* d_ws, size_t ws_size,
                              hipStream_t stream) {
  const float* x   = (const float*)d_in[0];
  const float* bw1 = (const float*)d_in[1];
  const float* sw1 = (const float*)d_in[2];
  const float* sc1 = (const float*)d_in[3];
  const float* bw2 = (const float*)d_in[4];
  const float* sw2 = (const float*)d_in[5];
  const float* sc2 = (const float*)d_in[6];
  float* out = (float*)d_out;
  uint* W = (uint*)d_ws;  // 432 dwords (54 entries x 8)
  const int B = in_sizes[0] / 784;  // 2048
  pack_w<<<1, 64, 0, stream>>>(bw1, sw1, sc1, bw2, sw2, sc2, W);
  kan_fwd<<<B, TPB, 0, stream>>>(x, W, out);
}

// Round 7
// 86.016 us; speedup vs baseline: 2.1188x; 1.1383x over previous
//
#include <hip/hip_runtime.h>
#include <math.h>

typedef _Float16 half_t;
typedef _Float16 h2 __attribute__((ext_vector_type(2)));
typedef unsigned int uint;
typedef unsigned long long u64;

#define TPB 256

// pack two floats into a half2 bit pattern
__device__ __forceinline__ uint pack_h2f(float a, float b) {
  half_t ha = (half_t)a, hb = (half_t)b;
  unsigned short ua = __builtin_bit_cast(unsigned short, ha);
  unsigned short ub = __builtin_bit_cast(unsigned short, hb);
  return (uint)ua | ((uint)ub << 16);
}

// acc += silu*bw + sum_g basis[g]*w[g]   (fp16 dot2 pairs, fp32 accumulate)
// w points at 5 uniform dwords: 4x half2 spline weights (*scaler), 1x f32 base_w
// NOTE: w is a GLOBAL pointer on purpose — uniform vector loads ride the TA/L1
// pipe and keep weight traffic OFF the LDS pipe (K2 vs K3 A/B evidence).
__device__ __forceinline__ float dot8(uint d0, uint d1, uint d2, uint d3,
                                      float sv, const uint* __restrict__ w,
                                      float acc) {
  acc = fmaf(sv, __uint_as_float(w[4]), acc);
#if __has_builtin(__builtin_amdgcn_fdot2)
  acc = __builtin_amdgcn_fdot2(__builtin_bit_cast(h2, d0), __builtin_bit_cast(h2, w[0]), acc, false);
  acc = __builtin_amdgcn_fdot2(__builtin_bit_cast(h2, d1), __builtin_bit_cast(h2, w[1]), acc, false);
  acc = __builtin_amdgcn_fdot2(__builtin_bit_cast(h2, d2), __builtin_bit_cast(h2, w[2]), acc, false);
  acc = __builtin_amdgcn_fdot2(__builtin_bit_cast(h2, d3), __builtin_bit_cast(h2, w[3]), acc, false);
#else
  uint dd[4] = {d0, d1, d2, d3};
#pragma unroll
  for (int k = 0; k < 4; ++k) {
    h2 f = __builtin_bit_cast(h2, dd[k]);
    h2 wv = __builtin_bit_cast(h2, w[k]);
    acc = fmaf((float)f.x, (float)wv.x, acc);
    acc = fmaf((float)f.y, (float)wv.y, acc);
  }
#endif
  return acc;
}

// Uniform-knot cubic B-spline + silu features -> 6-dword LDS slot.
// halves 0..7 = dense 8-basis (fp16), dword4 = silu (fp32), dword5 = pad.
// Dense fragment built in registers via a 128-bit shift scatter and stored
// with 2x ds_write_b64 + 1x b32 (proven R7 numerics, absmax 0.015625).
__device__ __forceinline__ void feat_store(float x, uint* __restrict__ slot) {
  float e = __expf(-x);
  float silu = x * __builtin_amdgcn_rcpf(1.0f + e);
  float s = fmaf(x, 2.5f, 5.5f);       // (x - (-2.2)) / 0.4
  float sf = floorf(s);
  float t = s - sf;
  int p = (int)sf - 3;                 // first nonzero basis index (may be <0)
  float omt = 1.0f - t, t2 = t * t;
  float B0 = (1.0f / 6.0f) * omt * omt * omt;
  float B3 = (1.0f / 6.0f) * t2 * t;
  float B1 = fmaf(0.5f * t, t2, 2.0f / 3.0f - t2);
  float B2 = 1.0f - B0 - B1 - B3;      // partition of unity
  u64 A = ((u64)pack_h2f(B2, B3) << 32) | pack_h2f(B0, B1);
  int n = p < 0 ? -p : 0;              // halves below 0: pre-drop
  A = (n >= 4) ? 0ull : (A >> (16 * n));
  int pc = p < 0 ? 0 : (p > 9 ? 9 : p);
  int sh = 16 * pc;                    // 0..144
  u64 lo = (sh < 64) ? (A << sh) : 0ull;
  u64 hi = (sh == 0) ? 0ull
         : (sh < 64) ? (A >> (64 - sh))
         : (sh < 128) ? (A << (sh - 64)) : 0ull;
  *(uint2*)slot = make_uint2((uint)lo, (uint)(lo >> 32));
  *(uint2*)(slot + 2) = make_uint2((uint)hi, (uint)(hi >> 32));
  slot[4] = __float_as_uint(silu);
}

// Precompute packed fp16 weights into d_ws (global; read via TA pipe):
// W[t*5]        t=o*9+tap        (layer 1, 18 entries)
// W[90 + q*5]   q=(o*2+ci)*9+tap (layer 2, 36 entries)
__global__ void pack_w(const float* __restrict__ bw1, const float* __restrict__ sw1,
                       const float* __restrict__ sc1, const float* __restrict__ bw2,
                       const float* __restrict__ sw2, const float* __restrict__ sc2,
                       uint* __restrict__ W) {
  const int t = threadIdx.x;
  if (t < 18) {
    const float scv = sc1[t];
    uint* dst = W + t * 5;
#pragma unroll
    for (int j = 0; j < 4; ++j)
      dst[j] = pack_h2f(sw1[t * 8 + 2 * j] * scv, sw1[t * 8 + 2 * j + 1] * scv);
    dst[4] = __float_as_uint(bw1[t]);
  } else if (t < 54) {
    const int q = t - 18;
    const float scv = sc2[q];
    uint* dst = W + 90 + q * 5;
#pragma unroll
    for (int j = 0; j < 4; ++j)
      dst[j] = pack_h2f(sw2[q * 8 + 2 * j] * scv, sw2[q * 8 + 2 * j + 1] * scv);
    dst[4] = __float_as_uint(bw2[q]);
  }
}

// R14: exact revert to the proven-best R7 structure (84.7/85.1 us), with ONE
// change: launch_bounds min-waves 5 -> 4. Discovered cap rule (R4/R5/R9):
// hipcc caps arch-VGPRs at ~floor(256/minwaves): w=5 capped R7 at 48 VGPRs,
// likely below natural demand (mild spill / strangled scheduling). w=4 gives
// a 64-VGPR budget. Occupancy is UNCHANGED: 31 KB LDS caps residency at 5
// blocks/CU regardless, so the extra registers are free.
__global__ __launch_bounds__(TPB, 4) void kan_fwd(
    const float* __restrict__ x, const uint* __restrict__ W,
    float* __restrict__ out)
{
  // 6 dwords (24 B) per pixel slot
  __shared__ __align__(16) uint lds[5400 + 2352];  // 31 KB -> 5 blocks/CU
  uint* F1 = lds;            // 900 slots (30x30 padded)
  uint* F2 = lds + 5400;     // 2 x 196 slots (14x14, unpadded)
  float* P = (float*)lds;    // stage>=3: 4*49*4 partials (F1 region is dead)

  const int tid = threadIdx.x;
  const float* xb = x + (size_t)blockIdx.x * 784;

  // ---- Stage 1: features of padded 30x30 input ----
  for (int ii = tid; ii < 900; ii += TPB) {
    int r = ii / 30, c = ii % 30;
    bool inter = ((uint)(r - 1) < 28u) && ((uint)(c - 1) < 28u);
    int xi = (r - 1) * 28 + (c - 1);
    xi = min(max(xi, 0), 783);
    float xv = xb[xi];
    xv = inter ? xv : 0.0f;              // padding pixels get features of 0
    feat_store(xv, F1 + ii * 6);
  }
  __syncthreads();

  // ---- Stage 2: layer-1 conv (2x2 pool quad per thread) + pool + features ----
  if (tid < 196) {
    const int ph = tid / 14, pw = tid % 14;
    float acc[2][4];
#pragma unroll
    for (int o = 0; o < 2; ++o)
#pragma unroll
      for (int q = 0; q < 4; ++q) acc[o][q] = 0.0f;
#pragma unroll
    for (int r = 0; r < 4; ++r) {
#pragma unroll
      for (int c = 0; c < 4; ++c) {
        const uint* sl = F1 + ((2 * ph + r) * 30 + (2 * pw + c)) * 6;
        uint2 a = *(const uint2*)sl;
        uint2 bq = *(const uint2*)(sl + 2);
        float sv = __uint_as_float(sl[4]);
#pragma unroll
        for (int dh = 0; dh < 2; ++dh) {
          if (r - dh < 0 || r - dh > 2) continue;
#pragma unroll
          for (int dw = 0; dw < 2; ++dw) {
            if (c - dw < 0 || c - dw > 2) continue;
            const int tap = (r - dh) * 3 + (c - dw);
#pragma unroll
            for (int o = 0; o < 2; ++o)
              acc[o][dh * 2 + dw] =
                  dot8(a.x, a.y, bq.x, bq.y, sv, W + (o * 9 + tap) * 5, acc[o][dh * 2 + dw]);
          }
        }
      }
    }
#pragma unroll
    for (int o = 0; o < 2; ++o) {
      float m = fmaxf(fmaxf(acc[o][0], acc[o][1]), fmaxf(acc[o][2], acc[o][3]));
      feat_store(m, F2 + (o * 196 + tid) * 6);
    }
  }
  __syncthreads();

  // ---- Stage 3: layer-2 conv; one wave per (o,ci), lane = 7x7 pool pos ----
  {
    const int wid = __builtin_amdgcn_readfirstlane(tid >> 6);  // = o*2+ci
    const int lane = tid & 63;
    // features of x=0 (padding): basis halves 2..5 = {1/48, 23/48, 23/48, 1/48}
    const uint F0d1 = pack_h2f(1.0f / 48.0f, 23.0f / 48.0f);
    const uint F0d2 = pack_h2f(23.0f / 48.0f, 1.0f / 48.0f);
    if (lane < 49) {
      const int ci = wid & 1;
      const int ph = lane / 7, pw = lane % 7;
      float pa[4] = {0.0f, 0.0f, 0.0f, 0.0f};
#pragma unroll
      for (int r = 0; r < 4; ++r) {
#pragma unroll
        for (int c = 0; c < 4; ++c) {
          int row = 2 * ph + r - 1, col = 2 * pw + c - 1;
          bool ok = ((uint)row < 14u) && ((uint)col < 14u);
          int rcl = min(max(row, 0), 13), ccl = min(max(col, 0), 13);
          const uint* sl = F2 + (ci * 196 + rcl * 14 + ccl) * 6;
          uint2 a = *(const uint2*)sl;
          uint2 bq = *(const uint2*)(sl + 2);
          float sv = ok ? __uint_as_float(sl[4]) : 0.0f;
          uint d0 = ok ? a.x : 0u;
          uint d1 = ok ? a.y : F0d1;
          uint d2 = ok ? bq.x : F0d2;
          uint d3 = ok ? bq.y : 0u;
#pragma unroll
          for (int dh = 0; dh < 2; ++dh) {
            if (r - dh < 0 || r - dh > 2) continue;
#pragma unroll
            for (int dw = 0; dw < 2; ++dw) {
              if (c - dw < 0 || c - dw > 2) continue;
              const int tap = (r - dh) * 3 + (c - dw);
              pa[dh * 2 + dw] =
                  dot8(d0, d1, d2, d3, sv, W + 90 + (wid * 9 + tap) * 5, pa[dh * 2 + dw]);
            }
          }
        }
      }
      *(float4*)&P[(wid * 49 + lane) * 4] = make_float4(pa[0], pa[1], pa[2], pa[3]);
    }
  }
  __syncthreads();

  // ---- Stage 4: sum input channels, 2x2 maxpool, write (2,7,7) flat ----
  if (tid < 98) {
    const int o = tid / 49, pos = tid % 49;
    const float4 p0 = *(const float4*)&P[((o * 2 + 0) * 49 + pos) * 4];
    const float4 p1 = *(const float4*)&P[((o * 2 + 1) * 49 + pos) * 4];
    float m = fmaxf(fmaxf(p0.x + p1.x, p0.y + p1.y), fmaxf(p0.z + p1.z, p0.w + p1.w));
    out[(size_t)blockIdx.x * 98 + tid] = m;
  }
}

extern "C" void kernel_launch(void* const* d_in, const int* in_sizes, int n_in,
                              void* d_out, int out_size, void* d_ws, size_t ws_size,
                              hipStream_t stream) {
  const float* x   = (const float*)d_in[0];
  const float* bw1 = (const float*)d_in[1];
  const float* sw1 = (const float*)d_in[2];
  const float* sc1 = (const float*)d_in[3];
  const float* bw2 = (const float*)d_in[4];
  const float* sw2 = (const float*)d_in[5];
  const float* sc2 = (const float*)d_in[6];
  float* out = (float*)d_out;
  uint* W = (uint*)d_ws;  // 270 dwords
  const int B = in_sizes[0] / 784;  // 2048
  pack_w<<<1, 64, 0, stream>>>(bw1, sw1, sc1, bw2, sw2, sc2, W);
  kan_fwd<<<B, TPB, 0, stream>>>(x, W, out);
}